// Round 2
// baseline (2926.436 us; speedup 1.0000x reference)
//
#include <hip/hip_runtime.h>
#include <hip/hip_fp16.h>

// TFNN: 3-layer TransformerConv GNN. h fp32, q/k/v fp16 (ws budget ~166MB).

#define D 128

// ---------------- CSR build ----------------
__global__ __launch_bounds__(256) void hist_kernel(const int* __restrict__ dst,
                                                   int* __restrict__ counts, int e) {
  int i = blockIdx.x * 256 + threadIdx.x;
  if (i < e) atomicAdd(&counts[dst[i]], 1);
}

__global__ __launch_bounds__(256) void scan_a_kernel(const int* __restrict__ counts,
                                                     int* __restrict__ incl,
                                                     int* __restrict__ bsum) {
  int gid = blockIdx.x * 256 + threadIdx.x;
  int lane = threadIdx.x & 63, wid = threadIdx.x >> 6;
  int v = counts[gid];
  int s = v;
  #pragma unroll
  for (int off = 1; off < 64; off <<= 1) {
    int t = __shfl_up(s, off, 64);
    if (lane >= off) s += t;
  }
  __shared__ int wsum[4];
  if (lane == 63) wsum[wid] = s;
  __syncthreads();
  #pragma unroll
  for (int w = 0; w < 3; ++w)
    if (wid > w) s += wsum[w];
  incl[gid] = s;
  if (threadIdx.x == 255) bsum[blockIdx.x] = s;
}

__global__ __launch_bounds__(512) void scan_b_kernel(int* __restrict__ bs) {
  int tid = threadIdx.x;
  int lane = tid & 63, wid = tid >> 6;
  int v = bs[tid];
  int s = v;
  #pragma unroll
  for (int off = 1; off < 64; off <<= 1) {
    int t = __shfl_up(s, off, 64);
    if (lane >= off) s += t;
  }
  __shared__ int wsum[8];
  if (lane == 63) wsum[wid] = s;
  __syncthreads();
  #pragma unroll
  for (int w = 0; w < 7; ++w)
    if (wid > w) s += wsum[w];
  bs[tid] = s - v;  // exclusive block prefix
}

__global__ __launch_bounds__(256) void scan_c_kernel(const int* __restrict__ incl,
                                                     const int* __restrict__ counts,
                                                     const int* __restrict__ bsum,
                                                     int* __restrict__ offs, int n, int e) {
  int gid = blockIdx.x * 256 + threadIdx.x;
  if (gid < n) offs[gid] = incl[gid] - counts[gid] + bsum[blockIdx.x];
  if (gid == 0) offs[n] = e;
}

__global__ __launch_bounds__(256) void scatter_kernel(const int* __restrict__ srcs,
                                                      const int* __restrict__ dsts,
                                                      const int* __restrict__ offs,
                                                      int* __restrict__ cursor,
                                                      int* __restrict__ csr_src,
                                                      int* __restrict__ csr_eid, int e) {
  int i = blockIdx.x * 256 + threadIdx.x;
  if (i >= e) return;
  int d = dsts[i];
  int slot = atomicAdd(&cursor[d], 1);
  int p = offs[d] + slot;
  csr_src[p] = srcs[i];
  csr_eid[p] = i;
}

// deterministic order: sort each node's incoming edge list by edge id
__global__ __launch_bounds__(256) void sort_kernel(const int* __restrict__ offs,
                                                   int* __restrict__ eid,
                                                   int* __restrict__ srcs, int n) {
  int i = blockIdx.x * 256 + threadIdx.x;
  if (i >= n) return;
  int b = offs[i], e = offs[i + 1];
  for (int p = b + 1; p < e; ++p) {
    int ke = eid[p], ks = srcs[p];
    int q = p - 1;
    while (q >= b && eid[q] > ke) {
      eid[q + 1] = eid[q]; srcs[q + 1] = srcs[q]; --q;
    }
    eid[q + 1] = ke; srcs[q + 1] = ks;
  }
}

// ---------------- typed stores ----------------
__device__ inline void store4(float* p, float4 v) { *(float4*)p = v; }
__device__ inline void store4(__half* p, float4 v) {
  __half2 h01 = __floats2half2_rn(v.x, v.y);
  __half2 h23 = __floats2half2_rn(v.z, v.w);
  uint2 u;
  u.x = *(unsigned int*)&h01;
  u.y = *(unsigned int*)&h23;
  *(uint2*)p = u;
}

// ---------------- fused row-tile GEMM: out_m = in @ W_m + b_m (up to 3 matrices) ----------------
template <int K, typename OT>
__global__ __launch_bounds__(256) void gemm3_kernel(
    const float* __restrict__ in,
    const float* __restrict__ W0, const float* __restrict__ b0, OT* __restrict__ o0,
    const float* __restrict__ W1, const float* __restrict__ b1, OT* __restrict__ o1,
    const float* __restrict__ W2, const float* __restrict__ b2, OT* __restrict__ o2) {
  __shared__ float tile[64 * K];
  const int tid = threadIdx.x;
  const size_t row0 = (size_t)blockIdx.x * 64;
  for (int i = tid; i < 64 * K / 4; i += 256) {
    int r = i / (K / 4), c = i % (K / 4);
    ((float4*)tile)[r * (K / 4) + c] = ((const float4*)(in + (row0 + r) * K))[c];
  }
  __syncthreads();
  const int tx = tid & 31;  // cols 4*tx .. 4*tx+3
  const int ty = tid >> 5;  // rows ty*8 .. ty*8+7
  #pragma unroll
  for (int m = 0; m < 3; ++m) {
    const float* W = (m == 0) ? W0 : (m == 1 ? W1 : W2);
    const float* b = (m == 0) ? b0 : (m == 1 ? b1 : b2);
    OT* o = (m == 0) ? o0 : (m == 1 ? o1 : o2);
    if (W == nullptr) continue;
    float acc[8][4];
    #pragma unroll
    for (int r = 0; r < 8; ++r)
      acc[r][0] = acc[r][1] = acc[r][2] = acc[r][3] = 0.f;
    for (int d4 = 0; d4 < K / 4; ++d4) {
      float4 w0 = *(const float4*)(W + (size_t)(d4 * 4 + 0) * 128 + tx * 4);
      float4 w1 = *(const float4*)(W + (size_t)(d4 * 4 + 1) * 128 + tx * 4);
      float4 w2 = *(const float4*)(W + (size_t)(d4 * 4 + 2) * 128 + tx * 4);
      float4 w3 = *(const float4*)(W + (size_t)(d4 * 4 + 3) * 128 + tx * 4);
      #pragma unroll
      for (int r = 0; r < 8; ++r) {
        float4 hh = *((const float4*)&tile[(ty * 8 + r) * K + d4 * 4]);
        acc[r][0] += hh.x * w0.x + hh.y * w1.x + hh.z * w2.x + hh.w * w3.x;
        acc[r][1] += hh.x * w0.y + hh.y * w1.y + hh.z * w2.y + hh.w * w3.y;
        acc[r][2] += hh.x * w0.z + hh.y * w1.z + hh.z * w2.z + hh.w * w3.z;
        acc[r][3] += hh.x * w0.w + hh.y * w1.w + hh.z * w2.w + hh.w * w3.w;
      }
    }
    float4 bias = ((const float4*)b)[tx];
    #pragma unroll
    for (int r = 0; r < 8; ++r) {
      float4 ov;
      ov.x = acc[r][0] + bias.x;
      ov.y = acc[r][1] + bias.y;
      ov.z = acc[r][2] + bias.z;
      ov.w = acc[r][3] + bias.w;
      store4(o + (row0 + ty * 8 + r) * 128 + tx * 4, ov);
    }
  }
}

// ---------------- node-centric transformer conv (one wave per node) ----------------
// online softmax over incoming edges; fuses edge proj, skip (h@ws+bs), relu; h updated in place.
__global__ __launch_bounds__(256) void node_kernel(
    const __half* __restrict__ q, const __half* __restrict__ k, const __half* __restrict__ v,
    float* __restrict__ h, const float* __restrict__ edge_attr,
    const float* __restrict__ we, const float* __restrict__ wsk, const float* __restrict__ bs,
    const int* __restrict__ offs, const int* __restrict__ csr_src,
    const int* __restrict__ csr_eid) {
  __shared__ float we_s[16 * 128];    // 8 KB
  __shared__ float ws_s[128 * 128];   // 64 KB
  for (int i = threadIdx.x; i < (16 * 128) / 4; i += 256)
    ((float4*)we_s)[i] = ((const float4*)we)[i];
  for (int i = threadIdx.x; i < (128 * 128) / 4; i += 256)
    ((float4*)ws_s)[i] = ((const float4*)wsk)[i];
  __syncthreads();

  const int wid = threadIdx.x >> 6, lane = threadIdx.x & 63;
  const int node = blockIdx.x * 4 + wid;
  const int c0 = lane * 2;
  const float inv_sqrt_d = 0.08838834764831845f;  // 1/sqrt(128)

  float2 qv = __half22float2(((const __half2*)q)[(size_t)node * 64 + lane]);
  qv.x *= inv_sqrt_d; qv.y *= inv_sqrt_d;

  // skip: sv = bs + h[node] @ ws
  float2 sv = *(const float2*)(bs + c0);
  const float4* hrow = (const float4*)(h + (size_t)node * D);
  #pragma unroll 4
  for (int d4 = 0; d4 < D / 4; ++d4) {
    float4 hh = hrow[d4];
    int dd = d4 * 4;
    float2 w0 = *(const float2*)&ws_s[(dd + 0) * D + c0];
    float2 w1 = *(const float2*)&ws_s[(dd + 1) * D + c0];
    float2 w2 = *(const float2*)&ws_s[(dd + 2) * D + c0];
    float2 w3 = *(const float2*)&ws_s[(dd + 3) * D + c0];
    sv.x += hh.x * w0.x + hh.y * w1.x + hh.z * w2.x + hh.w * w3.x;
    sv.y += hh.x * w0.y + hh.y * w1.y + hh.z * w2.y + hh.w * w3.y;
  }

  int eb = offs[node], ee = offs[node + 1];
  float m = -3.0e38f, den = 0.f;
  float2 acc = {0.f, 0.f};
  for (int p = eb; p < ee; ++p) {
    int src = csr_src[p];
    int eid = csr_eid[p];
    const float4* ea4 = (const float4*)(edge_attr + (size_t)eid * 16);
    float2 ev = {0.f, 0.f};
    #pragma unroll
    for (int f4 = 0; f4 < 4; ++f4) {
      float4 a = ea4[f4];
      int f = f4 * 4;
      float2 w0 = *(const float2*)&we_s[(f + 0) * D + c0];
      float2 w1 = *(const float2*)&we_s[(f + 1) * D + c0];
      float2 w2 = *(const float2*)&we_s[(f + 2) * D + c0];
      float2 w3 = *(const float2*)&we_s[(f + 3) * D + c0];
      ev.x += a.x * w0.x + a.y * w1.x + a.z * w2.x + a.w * w3.x;
      ev.y += a.x * w0.y + a.y * w1.y + a.z * w2.y + a.w * w3.y;
    }
    float2 kv = __half22float2(((const __half2*)k)[(size_t)src * 64 + lane]);
    float2 vv = __half22float2(((const __half2*)v)[(size_t)src * 64 + lane]);
    float pa = qv.x * (kv.x + ev.x) + qv.y * (kv.y + ev.y);
    #pragma unroll
    for (int off = 32; off > 0; off >>= 1) pa += __shfl_xor(pa, off, 64);
    float vjx = vv.x + ev.x, vjy = vv.y + ev.y;
    float mn = fmaxf(m, pa);
    float esc = __expf(m - mn);
    float ew = __expf(pa - mn);
    den = den * esc + ew;
    acc.x = acc.x * esc + ew * vjx;
    acc.y = acc.y * esc + ew * vjy;
    m = mn;
  }
  if (den > 0.f) {
    sv.x += acc.x / den;
    sv.y += acc.y / den;
  }
  sv.x = fmaxf(sv.x, 0.f);
  sv.y = fmaxf(sv.y, 0.f);
  *(float2*)(h + (size_t)node * D + c0) = sv;
}

// ---------------- segmented mean-pool (batch sorted) ----------------
__global__ __launch_bounds__(64) void pool_kernel(const float* __restrict__ h,
                                                  const int* __restrict__ batch,
                                                  float* __restrict__ hg,
                                                  float* __restrict__ cnt, int n) {
  int base = blockIdx.x * 128;
  int lane = threadIdx.x;
  float2 acc = {0.f, 0.f};
  float run = 0.f;
  int cur = batch[base];
  for (int i = 0; i < 128; ++i) {
    int node = base + i;
    int g = batch[node];
    if (g != cur) {
      atomicAdd(&hg[(size_t)cur * D + 2 * lane], acc.x);
      atomicAdd(&hg[(size_t)cur * D + 2 * lane + 1], acc.y);
      if (lane == 0) atomicAdd(&cnt[cur], run);
      acc.x = acc.y = 0.f; run = 0.f; cur = g;
    }
    float2 hv = *(const float2*)(h + (size_t)node * D + 2 * lane);
    acc.x += hv.x; acc.y += hv.y; run += 1.f;
  }
  atomicAdd(&hg[(size_t)cur * D + 2 * lane], acc.x);
  atomicAdd(&hg[(size_t)cur * D + 2 * lane + 1], acc.y);
  if (lane == 0) atomicAdd(&cnt[cur], run);
}

// ---------------- head: mean, fc2+relu, fc3 (one wave per graph) ----------------
__global__ __launch_bounds__(256) void head_kernel(const float* __restrict__ hg,
                                                   const float* __restrict__ cnt,
                                                   const float* __restrict__ w2,
                                                   const float* __restrict__ b2,
                                                   const float* __restrict__ w3,
                                                   const float* __restrict__ b3,
                                                   float* __restrict__ out) {
  __shared__ float w2s[128 * 16];
  __shared__ float rowb[4][128];
  for (int i = threadIdx.x; i < (128 * 16) / 4; i += 256)
    ((float4*)w2s)[i] = ((const float4*)w2)[i];
  int wid = threadIdx.x >> 6, lane = threadIdx.x & 63;
  int g = blockIdx.x * 4 + wid;
  float inv = 1.0f / fmaxf(cnt[g], 1.0f);
  rowb[wid][lane] = hg[(size_t)g * D + lane] * inv;
  rowb[wid][lane + 64] = hg[(size_t)g * D + 64 + lane] * inv;
  __syncthreads();
  float t = 0.f;
  if (lane < 16) {
    float a = b2[lane];
    for (int d = 0; d < 128; ++d) a += rowb[wid][d] * w2s[d * 16 + lane];
    t = fmaxf(a, 0.f) * w3[lane];
  }
  #pragma unroll
  for (int off = 8; off > 0; off >>= 1) t += __shfl_xor(t, off, 64);
  if (lane == 0) out[g] = t + b3[0];
}

// ---------------- launch ----------------
extern "C" void kernel_launch(void* const* d_in, const int* in_sizes, int n_in,
                              void* d_out, int out_size, void* d_ws, size_t ws_size,
                              hipStream_t stream) {
  const float* x = (const float*)d_in[0];
  const int* eidx = (const int*)d_in[1];
  const float* eattr = (const float*)d_in[2];
  const int* batch = (const int*)d_in[3];
  const float* fc1_w = (const float*)d_in[4];
  const float* fc1_b = (const float*)d_in[5];
  const float* WQ[3] = {(const float*)d_in[6], (const float*)d_in[15], (const float*)d_in[24]};
  const float* BQ[3] = {(const float*)d_in[7], (const float*)d_in[16], (const float*)d_in[25]};
  const float* WK[3] = {(const float*)d_in[8], (const float*)d_in[17], (const float*)d_in[26]};
  const float* BK[3] = {(const float*)d_in[9], (const float*)d_in[18], (const float*)d_in[27]};
  const float* WV[3] = {(const float*)d_in[10], (const float*)d_in[19], (const float*)d_in[28]};
  const float* BV[3] = {(const float*)d_in[11], (const float*)d_in[20], (const float*)d_in[29]};
  const float* WE[3] = {(const float*)d_in[12], (const float*)d_in[21], (const float*)d_in[30]};
  const float* WS[3] = {(const float*)d_in[13], (const float*)d_in[22], (const float*)d_in[31]};
  const float* BS[3] = {(const float*)d_in[14], (const float*)d_in[23], (const float*)d_in[32]};
  const float* fc2_w = (const float*)d_in[33];
  const float* fc2_b = (const float*)d_in[34];
  const float* fc3_w = (const float*)d_in[35];
  const float* fc3_b = (const float*)d_in[36];

  const int N = in_sizes[0] / 64;
  const int E = in_sizes[1] / 2;
  const int G = out_size;  // DIM_OUT = 1
  const int* srcs = eidx;
  const int* dsts = eidx + E;
  const size_t ND = (size_t)N * D;

  char* base = (char*)d_ws;
  size_t off = 0;
  auto alloc = [&](size_t bytes) {
    void* p = base + off;
    off = (off + bytes + 255) & ~(size_t)255;
    return p;
  };
  // zeroed region first (hg, cnt, counts, cursor contiguous — all sizes multiple of 256B)
  float* hg = (float*)alloc((size_t)G * D * 4);
  float* cntf = (float*)alloc((size_t)G * 4);
  int* counts = (int*)alloc((size_t)N * 4);
  int* cursor = (int*)alloc((size_t)N * 4);
  size_t zero_bytes = (size_t)G * D * 4 + (size_t)G * 4 + 2 * (size_t)N * 4;
  int* incl = (int*)alloc((size_t)N * 4);
  int* offs = (int*)alloc((size_t)(N + 4) * 4);
  int* bsum = (int*)alloc(512 * 4);
  int* csr_src = (int*)alloc((size_t)E * 4);
  int* csr_eid = (int*)alloc((size_t)E * 4);
  float* h = (float*)alloc(ND * 4);
  __half* q = (__half*)alloc(ND * 2);
  __half* k = (__half*)alloc(ND * 2);
  __half* v = (__half*)alloc(ND * 2);
  if (off > ws_size) return;  // ws too small (diagnostic: stub-identical absmax)

  hipMemsetAsync(hg, 0, zero_bytes, stream);

  // CSR build (deterministic after sort)
  hist_kernel<<<E / 256, 256, 0, stream>>>(dsts, counts, E);
  scan_a_kernel<<<N / 256, 256, 0, stream>>>(counts, incl, bsum);
  scan_b_kernel<<<1, 512, 0, stream>>>(bsum);
  scan_c_kernel<<<N / 256, 256, 0, stream>>>(incl, counts, bsum, offs, N, E);
  scatter_kernel<<<E / 256, 256, 0, stream>>>(srcs, dsts, offs, cursor, csr_src, csr_eid, E);
  sort_kernel<<<N / 256, 256, 0, stream>>>(offs, csr_eid, csr_src, N);

  // fc1: h = x @ fc1_w + fc1_b
  gemm3_kernel<64, float><<<N / 64, 256, 0, stream>>>(x, fc1_w, fc1_b, h,
                                                      nullptr, nullptr, nullptr,
                                                      nullptr, nullptr, nullptr);
  // 3 transformer-conv layers
  for (int l = 0; l < 3; ++l) {
    gemm3_kernel<128, __half><<<N / 64, 256, 0, stream>>>(h, WQ[l], BQ[l], q, WK[l], BK[l], k,
                                                          WV[l], BV[l], v);
    node_kernel<<<N / 4, 256, 0, stream>>>(q, k, v, h, eattr, WE[l], WS[l], BS[l],
                                           offs, csr_src, csr_eid);
  }

  // mean pool + head
  pool_kernel<<<N / 128, 64, 0, stream>>>(h, batch, hg, cntf, N);
  head_kernel<<<G / 4, 256, 0, stream>>>(hg, cntf, fc2_w, fc2_b, fc3_w, fc3_b, (float*)d_out);
}

// Round 3
// 1176.240 us; speedup vs baseline: 2.4880x; 2.4880x over previous
//
#include <hip/hip_runtime.h>
#include <hip/hip_fp16.h>

// TFNN: 3-layer TransformerConv GNN. h fp32, q/k/v fp16.
// Round 3: skip matvec fused into qkv GEMM (s overwrites h); node_kernel is
// LDS-free with we in registers + 2-deep pipelined edge loop.

#define D 128

// ---------------- CSR build ----------------
__global__ __launch_bounds__(256) void hist_kernel(const int* __restrict__ dst,
                                                   int* __restrict__ counts, int e) {
  int i = blockIdx.x * 256 + threadIdx.x;
  if (i < e) atomicAdd(&counts[dst[i]], 1);
}

__global__ __launch_bounds__(256) void scan_a_kernel(const int* __restrict__ counts,
                                                     int* __restrict__ incl,
                                                     int* __restrict__ bsum) {
  int gid = blockIdx.x * 256 + threadIdx.x;
  int lane = threadIdx.x & 63, wid = threadIdx.x >> 6;
  int v = counts[gid];
  int s = v;
  #pragma unroll
  for (int off = 1; off < 64; off <<= 1) {
    int t = __shfl_up(s, off, 64);
    if (lane >= off) s += t;
  }
  __shared__ int wsum[4];
  if (lane == 63) wsum[wid] = s;
  __syncthreads();
  #pragma unroll
  for (int w = 0; w < 3; ++w)
    if (wid > w) s += wsum[w];
  incl[gid] = s;
  if (threadIdx.x == 255) bsum[blockIdx.x] = s;
}

__global__ __launch_bounds__(512) void scan_b_kernel(int* __restrict__ bs) {
  int tid = threadIdx.x;
  int lane = tid & 63, wid = tid >> 6;
  int v = bs[tid];
  int s = v;
  #pragma unroll
  for (int off = 1; off < 64; off <<= 1) {
    int t = __shfl_up(s, off, 64);
    if (lane >= off) s += t;
  }
  __shared__ int wsum[8];
  if (lane == 63) wsum[wid] = s;
  __syncthreads();
  #pragma unroll
  for (int w = 0; w < 7; ++w)
    if (wid > w) s += wsum[w];
  bs[tid] = s - v;  // exclusive block prefix
}

__global__ __launch_bounds__(256) void scan_c_kernel(const int* __restrict__ incl,
                                                     const int* __restrict__ counts,
                                                     const int* __restrict__ bsum,
                                                     int* __restrict__ offs, int n, int e) {
  int gid = blockIdx.x * 256 + threadIdx.x;
  if (gid < n) offs[gid] = incl[gid] - counts[gid] + bsum[blockIdx.x];
  if (gid == 0) offs[n] = e;
}

__global__ __launch_bounds__(256) void scatter_kernel(const int* __restrict__ srcs,
                                                      const int* __restrict__ dsts,
                                                      const int* __restrict__ offs,
                                                      int* __restrict__ cursor,
                                                      int* __restrict__ csr_src,
                                                      int* __restrict__ csr_eid, int e) {
  int i = blockIdx.x * 256 + threadIdx.x;
  if (i >= e) return;
  int d = dsts[i];
  int slot = atomicAdd(&cursor[d], 1);
  int p = offs[d] + slot;
  csr_src[p] = srcs[i];
  csr_eid[p] = i;
}

// deterministic order: sort each node's incoming edge list by edge id
__global__ __launch_bounds__(256) void sort_kernel(const int* __restrict__ offs,
                                                   int* __restrict__ eid,
                                                   int* __restrict__ srcs, int n) {
  int i = blockIdx.x * 256 + threadIdx.x;
  if (i >= n) return;
  int b = offs[i], e = offs[i + 1];
  for (int p = b + 1; p < e; ++p) {
    int ke = eid[p], ks = srcs[p];
    int q = p - 1;
    while (q >= b && eid[q] > ke) {
      eid[q + 1] = eid[q]; srcs[q + 1] = srcs[q]; --q;
    }
    eid[q + 1] = ke; srcs[q + 1] = ks;
  }
}

// ---------------- typed stores ----------------
__device__ inline void store4(float* p, float4 v) { *(float4*)p = v; }
__device__ inline void store4(__half* p, float4 v) {
  __half2 h01 = __floats2half2_rn(v.x, v.y);
  __half2 h23 = __floats2half2_rn(v.z, v.w);
  uint2 u;
  u.x = *(unsigned int*)&h01;
  u.y = *(unsigned int*)&h23;
  *(uint2*)p = u;
}

// ---------------- fc1 row-tile GEMM ----------------
__global__ __launch_bounds__(256) void fc1_kernel(const float* __restrict__ in,
                                                  const float* __restrict__ W,
                                                  const float* __restrict__ b,
                                                  float* __restrict__ o) {
  const int K = 64;
  __shared__ float tile[64 * K];
  const int tid = threadIdx.x;
  const size_t row0 = (size_t)blockIdx.x * 64;
  for (int i = tid; i < 64 * K / 4; i += 256) {
    int r = i / (K / 4), c = i % (K / 4);
    ((float4*)tile)[r * (K / 4) + c] = ((const float4*)(in + (row0 + r) * K))[c];
  }
  __syncthreads();
  const int tx = tid & 31;
  const int ty = tid >> 5;
  float acc[8][4];
  #pragma unroll
  for (int r = 0; r < 8; ++r)
    acc[r][0] = acc[r][1] = acc[r][2] = acc[r][3] = 0.f;
  for (int d4 = 0; d4 < K / 4; ++d4) {
    float4 w0 = *(const float4*)(W + (size_t)(d4 * 4 + 0) * 128 + tx * 4);
    float4 w1 = *(const float4*)(W + (size_t)(d4 * 4 + 1) * 128 + tx * 4);
    float4 w2 = *(const float4*)(W + (size_t)(d4 * 4 + 2) * 128 + tx * 4);
    float4 w3 = *(const float4*)(W + (size_t)(d4 * 4 + 3) * 128 + tx * 4);
    #pragma unroll
    for (int r = 0; r < 8; ++r) {
      float4 hh = *((const float4*)&tile[(ty * 8 + r) * K + d4 * 4]);
      acc[r][0] += hh.x * w0.x + hh.y * w1.x + hh.z * w2.x + hh.w * w3.x;
      acc[r][1] += hh.x * w0.y + hh.y * w1.y + hh.z * w2.y + hh.w * w3.y;
      acc[r][2] += hh.x * w0.z + hh.y * w1.z + hh.z * w2.z + hh.w * w3.z;
      acc[r][3] += hh.x * w0.w + hh.y * w1.w + hh.z * w2.w + hh.w * w3.w;
    }
  }
  float4 bias = ((const float4*)b)[tx];
  #pragma unroll
  for (int r = 0; r < 8; ++r) {
    float4 ov;
    ov.x = acc[r][0] + bias.x;
    ov.y = acc[r][1] + bias.y;
    ov.z = acc[r][2] + bias.z;
    ov.w = acc[r][3] + bias.w;
    store4(o + (row0 + ty * 8 + r) * 128 + tx * 4, ov);
  }
}

// ---------------- fused q/k/v/skip GEMM: q,k,v fp16; s = h@ws+bs overwrites h ----------------
__global__ __launch_bounds__(256) void gemm_qkvs_kernel(
    float* __restrict__ h,  // in: h, out: s (rows owned by this block)
    const float* __restrict__ Wq, const float* __restrict__ bq, __half* __restrict__ oq,
    const float* __restrict__ Wk, const float* __restrict__ bk, __half* __restrict__ ok,
    const float* __restrict__ Wv, const float* __restrict__ bv, __half* __restrict__ ov,
    const float* __restrict__ Ws, const float* __restrict__ bs) {
  const int K = 128;
  __shared__ float tile[64 * K];
  const int tid = threadIdx.x;
  const size_t row0 = (size_t)blockIdx.x * 64;
  for (int i = tid; i < 64 * K / 4; i += 256) {
    int r = i / (K / 4), c = i % (K / 4);
    ((float4*)tile)[r * (K / 4) + c] = ((const float4*)(h + (row0 + r) * K))[c];
  }
  __syncthreads();
  const int tx = tid & 31;
  const int ty = tid >> 5;
  #pragma unroll
  for (int m = 0; m < 4; ++m) {
    const float* W = (m == 0) ? Wq : (m == 1 ? Wk : (m == 2 ? Wv : Ws));
    const float* b = (m == 0) ? bq : (m == 1 ? bk : (m == 2 ? bv : bs));
    float acc[8][4];
    #pragma unroll
    for (int r = 0; r < 8; ++r)
      acc[r][0] = acc[r][1] = acc[r][2] = acc[r][3] = 0.f;
    for (int d4 = 0; d4 < K / 4; ++d4) {
      float4 w0 = *(const float4*)(W + (size_t)(d4 * 4 + 0) * 128 + tx * 4);
      float4 w1 = *(const float4*)(W + (size_t)(d4 * 4 + 1) * 128 + tx * 4);
      float4 w2 = *(const float4*)(W + (size_t)(d4 * 4 + 2) * 128 + tx * 4);
      float4 w3 = *(const float4*)(W + (size_t)(d4 * 4 + 3) * 128 + tx * 4);
      #pragma unroll
      for (int r = 0; r < 8; ++r) {
        float4 hh = *((const float4*)&tile[(ty * 8 + r) * K + d4 * 4]);
        acc[r][0] += hh.x * w0.x + hh.y * w1.x + hh.z * w2.x + hh.w * w3.x;
        acc[r][1] += hh.x * w0.y + hh.y * w1.y + hh.z * w2.y + hh.w * w3.y;
        acc[r][2] += hh.x * w0.z + hh.y * w1.z + hh.z * w2.z + hh.w * w3.z;
        acc[r][3] += hh.x * w0.w + hh.y * w1.w + hh.z * w2.w + hh.w * w3.w;
      }
    }
    float4 bias = ((const float4*)b)[tx];
    #pragma unroll
    for (int r = 0; r < 8; ++r) {
      float4 ovv;
      ovv.x = acc[r][0] + bias.x;
      ovv.y = acc[r][1] + bias.y;
      ovv.z = acc[r][2] + bias.z;
      ovv.w = acc[r][3] + bias.w;
      size_t idx = (row0 + ty * 8 + r) * 128 + tx * 4;
      if (m == 0) store4(oq + idx, ovv);
      else if (m == 1) store4(ok + idx, ovv);
      else if (m == 2) store4(ov + idx, ovv);
      else store4(h + idx, ovv);  // safe: this block's rows already staged in LDS
    }
  }
}

// ---------------- node-centric transformer conv (one wave per node, LDS-free) ----------------
// h holds s = h_prev@ws+bs on entry; writes relu(s + softmax-agg) back to h.
__global__ __launch_bounds__(256) void node_kernel(
    const __half* __restrict__ q, const __half* __restrict__ k, const __half* __restrict__ v,
    float* __restrict__ h, const float* __restrict__ edge_attr,
    const float* __restrict__ we,
    const int* __restrict__ offs, const int* __restrict__ csr_src,
    const int* __restrict__ csr_eid) {
  const int wid = threadIdx.x >> 6, lane = threadIdx.x & 63;
  const int node = __builtin_amdgcn_readfirstlane(blockIdx.x * 4 + wid);
  const int c0 = lane * 2;
  const float inv_sqrt_d = 0.08838834764831845f;  // 1/sqrt(128)

  // we columns (c0, c0+1) for all 16 bond features -> registers
  float2 wreg[16];
  #pragma unroll
  for (int f = 0; f < 16; ++f)
    wreg[f] = *(const float2*)(we + f * D + c0);

  float2 qv = __half22float2(((const __half2*)q)[(size_t)node * 64 + lane]);
  qv.x *= inv_sqrt_d; qv.y *= inv_sqrt_d;
  float2 sv = *(const float2*)(h + (size_t)node * D + c0);

  const int eb = offs[node], ee = offs[node + 1];
  float m = -3.0e38f, den = 0.f, accx = 0.f, accy = 0.f;

  // 2-deep software pipeline over incoming edges
  float4 a0n = {0,0,0,0}, a1n = {0,0,0,0}, a2n = {0,0,0,0}, a3n = {0,0,0,0};
  float2 kvn = {0.f, 0.f}, vvn = {0.f, 0.f};
  int p = eb;
  if (p < ee) {
    int src = __builtin_amdgcn_readfirstlane(csr_src[p]);
    int eid = __builtin_amdgcn_readfirstlane(csr_eid[p]);
    const float* ea = edge_attr + (size_t)eid * 16;
    a0n = *(const float4*)(ea + 0);  a1n = *(const float4*)(ea + 4);
    a2n = *(const float4*)(ea + 8);  a3n = *(const float4*)(ea + 12);
    kvn = __half22float2(((const __half2*)k)[(size_t)src * 64 + lane]);
    vvn = __half22float2(((const __half2*)v)[(size_t)src * 64 + lane]);
  }
  while (p < ee) {
    float4 a0 = a0n, a1 = a1n, a2 = a2n, a3 = a3n;
    float2 kv = kvn, vv = vvn;
    ++p;
    if (p < ee) {
      int src = __builtin_amdgcn_readfirstlane(csr_src[p]);
      int eid = __builtin_amdgcn_readfirstlane(csr_eid[p]);
      const float* ea = edge_attr + (size_t)eid * 16;
      a0n = *(const float4*)(ea + 0);  a1n = *(const float4*)(ea + 4);
      a2n = *(const float4*)(ea + 8);  a3n = *(const float4*)(ea + 12);
      kvn = __half22float2(((const __half2*)k)[(size_t)src * 64 + lane]);
      vvn = __half22float2(((const __half2*)v)[(size_t)src * 64 + lane]);
    }
    // edge projection: ev = ea @ we (2 columns per lane)
    float ea16[16] = {a0.x, a0.y, a0.z, a0.w, a1.x, a1.y, a1.z, a1.w,
                      a2.x, a2.y, a2.z, a2.w, a3.x, a3.y, a3.z, a3.w};
    float evx = 0.f, evy = 0.f;
    #pragma unroll
    for (int f = 0; f < 16; ++f) {
      evx += ea16[f] * wreg[f].x;
      evy += ea16[f] * wreg[f].y;
    }
    float pa = qv.x * (kv.x + evx) + qv.y * (kv.y + evy);
    #pragma unroll
    for (int off = 32; off > 0; off >>= 1) pa += __shfl_xor(pa, off, 64);
    float vjx = vv.x + evx, vjy = vv.y + evy;
    float mn = fmaxf(m, pa);
    float esc = __expf(m - mn);
    float ew = __expf(pa - mn);
    den = den * esc + ew;
    accx = accx * esc + ew * vjx;
    accy = accy * esc + ew * vjy;
    m = mn;
  }
  if (den > 0.f) {
    sv.x += accx / den;
    sv.y += accy / den;
  }
  sv.x = fmaxf(sv.x, 0.f);
  sv.y = fmaxf(sv.y, 0.f);
  *(float2*)(h + (size_t)node * D + c0) = sv;
}

// ---------------- segmented mean-pool (batch sorted) ----------------
__global__ __launch_bounds__(64) void pool_kernel(const float* __restrict__ h,
                                                  const int* __restrict__ batch,
                                                  float* __restrict__ hg,
                                                  float* __restrict__ cnt, int n) {
  int base = blockIdx.x * 128;
  int lane = threadIdx.x;
  float2 acc = {0.f, 0.f};
  float run = 0.f;
  int cur = batch[base];
  for (int i = 0; i < 128; ++i) {
    int node = base + i;
    int g = batch[node];
    if (g != cur) {
      atomicAdd(&hg[(size_t)cur * D + 2 * lane], acc.x);
      atomicAdd(&hg[(size_t)cur * D + 2 * lane + 1], acc.y);
      if (lane == 0) atomicAdd(&cnt[cur], run);
      acc.x = acc.y = 0.f; run = 0.f; cur = g;
    }
    float2 hv = *(const float2*)(h + (size_t)node * D + 2 * lane);
    acc.x += hv.x; acc.y += hv.y; run += 1.f;
  }
  atomicAdd(&hg[(size_t)cur * D + 2 * lane], acc.x);
  atomicAdd(&hg[(size_t)cur * D + 2 * lane + 1], acc.y);
  if (lane == 0) atomicAdd(&cnt[cur], run);
}

// ---------------- head: mean, fc2+relu, fc3 (one wave per graph) ----------------
__global__ __launch_bounds__(256) void head_kernel(const float* __restrict__ hg,
                                                   const float* __restrict__ cnt,
                                                   const float* __restrict__ w2,
                                                   const float* __restrict__ b2,
                                                   const float* __restrict__ w3,
                                                   const float* __restrict__ b3,
                                                   float* __restrict__ out) {
  __shared__ float w2s[128 * 16];
  __shared__ float rowb[4][128];
  for (int i = threadIdx.x; i < (128 * 16) / 4; i += 256)
    ((float4*)w2s)[i] = ((const float4*)w2)[i];
  int wid = threadIdx.x >> 6, lane = threadIdx.x & 63;
  int g = blockIdx.x * 4 + wid;
  float inv = 1.0f / fmaxf(cnt[g], 1.0f);
  rowb[wid][lane] = hg[(size_t)g * D + lane] * inv;
  rowb[wid][lane + 64] = hg[(size_t)g * D + 64 + lane] * inv;
  __syncthreads();
  float t = 0.f;
  if (lane < 16) {
    float a = b2[lane];
    for (int d = 0; d < 128; ++d) a += rowb[wid][d] * w2s[d * 16 + lane];
    t = fmaxf(a, 0.f) * w3[lane];
  }
  #pragma unroll
  for (int off = 8; off > 0; off >>= 1) t += __shfl_xor(t, off, 64);
  if (lane == 0) out[g] = t + b3[0];
}

// ---------------- launch ----------------
extern "C" void kernel_launch(void* const* d_in, const int* in_sizes, int n_in,
                              void* d_out, int out_size, void* d_ws, size_t ws_size,
                              hipStream_t stream) {
  const float* x = (const float*)d_in[0];
  const int* eidx = (const int*)d_in[1];
  const float* eattr = (const float*)d_in[2];
  const int* batch = (const int*)d_in[3];
  const float* fc1_w = (const float*)d_in[4];
  const float* fc1_b = (const float*)d_in[5];
  const float* WQ[3] = {(const float*)d_in[6], (const float*)d_in[15], (const float*)d_in[24]};
  const float* BQ[3] = {(const float*)d_in[7], (const float*)d_in[16], (const float*)d_in[25]};
  const float* WK[3] = {(const float*)d_in[8], (const float*)d_in[17], (const float*)d_in[26]};
  const float* BK[3] = {(const float*)d_in[9], (const float*)d_in[18], (const float*)d_in[27]};
  const float* WV[3] = {(const float*)d_in[10], (const float*)d_in[19], (const float*)d_in[28]};
  const float* BV[3] = {(const float*)d_in[11], (const float*)d_in[20], (const float*)d_in[29]};
  const float* WE[3] = {(const float*)d_in[12], (const float*)d_in[21], (const float*)d_in[30]};
  const float* WS[3] = {(const float*)d_in[13], (const float*)d_in[22], (const float*)d_in[31]};
  const float* BS[3] = {(const float*)d_in[14], (const float*)d_in[23], (const float*)d_in[32]};
  const float* fc2_w = (const float*)d_in[33];
  const float* fc2_b = (const float*)d_in[34];
  const float* fc3_w = (const float*)d_in[35];
  const float* fc3_b = (const float*)d_in[36];

  const int N = in_sizes[0] / 64;
  const int E = in_sizes[1] / 2;
  const int G = out_size;  // DIM_OUT = 1
  const int* srcs = eidx;
  const int* dsts = eidx + E;
  const size_t ND = (size_t)N * D;

  char* base = (char*)d_ws;
  size_t off = 0;
  auto alloc = [&](size_t bytes) {
    void* p = base + off;
    off = (off + bytes + 255) & ~(size_t)255;
    return p;
  };
  // zeroed region first (hg, cnt, counts, cursor contiguous — all sizes multiple of 256B)
  float* hg = (float*)alloc((size_t)G * D * 4);
  float* cntf = (float*)alloc((size_t)G * 4);
  int* counts = (int*)alloc((size_t)N * 4);
  int* cursor = (int*)alloc((size_t)N * 4);
  size_t zero_bytes = (size_t)G * D * 4 + (size_t)G * 4 + 2 * (size_t)N * 4;
  int* incl = (int*)alloc((size_t)N * 4);
  int* offs = (int*)alloc((size_t)(N + 4) * 4);
  int* bsum = (int*)alloc(512 * 4);
  int* csr_src = (int*)alloc((size_t)E * 4);
  int* csr_eid = (int*)alloc((size_t)E * 4);
  float* h = (float*)alloc(ND * 4);
  __half* q = (__half*)alloc(ND * 2);
  __half* k = (__half*)alloc(ND * 2);
  __half* v = (__half*)alloc(ND * 2);
  if (off > ws_size) return;  // ws too small (diagnostic: stub-identical absmax)

  hipMemsetAsync(hg, 0, zero_bytes, stream);

  // CSR build (deterministic after sort)
  hist_kernel<<<E / 256, 256, 0, stream>>>(dsts, counts, E);
  scan_a_kernel<<<N / 256, 256, 0, stream>>>(counts, incl, bsum);
  scan_b_kernel<<<1, 512, 0, stream>>>(bsum);
  scan_c_kernel<<<N / 256, 256, 0, stream>>>(incl, counts, bsum, offs, N, E);
  scatter_kernel<<<E / 256, 256, 0, stream>>>(srcs, dsts, offs, cursor, csr_src, csr_eid, E);
  sort_kernel<<<N / 256, 256, 0, stream>>>(offs, csr_eid, csr_src, N);

  // fc1: h = x @ fc1_w + fc1_b
  fc1_kernel<<<N / 64, 256, 0, stream>>>(x, fc1_w, fc1_b, h);

  // 3 transformer-conv layers
  for (int l = 0; l < 3; ++l) {
    gemm_qkvs_kernel<<<N / 64, 256, 0, stream>>>(h, WQ[l], BQ[l], q, WK[l], BK[l], k,
                                                 WV[l], BV[l], v, WS[l], BS[l]);
    node_kernel<<<N / 4, 256, 0, stream>>>(q, k, v, h, eattr, WE[l],
                                           offs, csr_src, csr_eid);
  }

  // mean pool + head
  pool_kernel<<<N / 128, 64, 0, stream>>>(h, batch, hg, cntf, N);
  head_kernel<<<G / 4, 256, 0, stream>>>(hg, cntf, fc2_w, fc2_b, fc3_w, fc3_b, (float*)d_out);
}

// Round 4
// 890.685 us; speedup vs baseline: 3.2856x; 1.3206x over previous
//
#include <hip/hip_runtime.h>
#include <hip/hip_fp16.h>

// TFNN: 3-layer TransformerConv GNN.
// Round 4: fp16-MFMA GEMMs (16x16x32_f16, fp32 accum), weights pre-transposed
// to fp16; node_kernel unchanged (LDS-free, we-in-registers, 2-deep pipeline).

#define D 128

typedef _Float16 half8 __attribute__((ext_vector_type(8)));
typedef float f32x4 __attribute__((ext_vector_type(4)));

// ---------------- CSR build ----------------
__global__ __launch_bounds__(256) void hist_kernel(const int* __restrict__ dst,
                                                   int* __restrict__ counts, int e) {
  int i = blockIdx.x * 256 + threadIdx.x;
  if (i < e) atomicAdd(&counts[dst[i]], 1);
}

__global__ __launch_bounds__(256) void scan_a_kernel(const int* __restrict__ counts,
                                                     int* __restrict__ incl,
                                                     int* __restrict__ bsum) {
  int gid = blockIdx.x * 256 + threadIdx.x;
  int lane = threadIdx.x & 63, wid = threadIdx.x >> 6;
  int v = counts[gid];
  int s = v;
  #pragma unroll
  for (int off = 1; off < 64; off <<= 1) {
    int t = __shfl_up(s, off, 64);
    if (lane >= off) s += t;
  }
  __shared__ int wsum[4];
  if (lane == 63) wsum[wid] = s;
  __syncthreads();
  #pragma unroll
  for (int w = 0; w < 3; ++w)
    if (wid > w) s += wsum[w];
  incl[gid] = s;
  if (threadIdx.x == 255) bsum[blockIdx.x] = s;
}

__global__ __launch_bounds__(512) void scan_b_kernel(int* __restrict__ bs) {
  int tid = threadIdx.x;
  int lane = tid & 63, wid = tid >> 6;
  int v = bs[tid];
  int s = v;
  #pragma unroll
  for (int off = 1; off < 64; off <<= 1) {
    int t = __shfl_up(s, off, 64);
    if (lane >= off) s += t;
  }
  __shared__ int wsum[8];
  if (lane == 63) wsum[wid] = s;
  __syncthreads();
  #pragma unroll
  for (int w = 0; w < 7; ++w)
    if (wid > w) s += wsum[w];
  bs[tid] = s - v;  // exclusive block prefix
}

__global__ __launch_bounds__(256) void scan_c_kernel(const int* __restrict__ incl,
                                                     const int* __restrict__ counts,
                                                     const int* __restrict__ bsum,
                                                     int* __restrict__ offs, int n, int e) {
  int gid = blockIdx.x * 256 + threadIdx.x;
  if (gid < n) offs[gid] = incl[gid] - counts[gid] + bsum[blockIdx.x];
  if (gid == 0) offs[n] = e;
}

__global__ __launch_bounds__(256) void scatter_kernel(const int* __restrict__ srcs,
                                                      const int* __restrict__ dsts,
                                                      const int* __restrict__ offs,
                                                      int* __restrict__ cursor,
                                                      int* __restrict__ csr_src,
                                                      int* __restrict__ csr_eid, int e) {
  int i = blockIdx.x * 256 + threadIdx.x;
  if (i >= e) return;
  int d = dsts[i];
  int slot = atomicAdd(&cursor[d], 1);
  int p = offs[d] + slot;
  csr_src[p] = srcs[i];
  csr_eid[p] = i;
}

// deterministic order: sort each node's incoming edge list by edge id
__global__ __launch_bounds__(256) void sort_kernel(const int* __restrict__ offs,
                                                   int* __restrict__ eid,
                                                   int* __restrict__ srcs, int n) {
  int i = blockIdx.x * 256 + threadIdx.x;
  if (i >= n) return;
  int b = offs[i], e = offs[i + 1];
  for (int p = b + 1; p < e; ++p) {
    int ke = eid[p], ks = srcs[p];
    int q = p - 1;
    while (q >= b && eid[q] > ke) {
      eid[q + 1] = eid[q]; srcs[q + 1] = srcs[q]; --q;
    }
    eid[q + 1] = ke; srcs[q + 1] = ks;
  }
}

// ---------------- weight transpose + fp16 convert: out[n][kk] = W[kk][n] ----------------
__global__ __launch_bounds__(256) void convw_kernel(const float* __restrict__ W,
                                                    __half* __restrict__ out,
                                                    int ncols, int K) {
  int idx = blockIdx.x * 256 + threadIdx.x;
  if (idx >= ncols * K) return;
  int n = idx / K, kk = idx - n * K;
  out[idx] = __float2half(W[(size_t)kk * ncols + n]);
}

// bias concat: out[0:512] = bq|bk|bv|bs
__global__ __launch_bounds__(256) void bcat_kernel(const float* __restrict__ bq,
                                                   const float* __restrict__ bk,
                                                   const float* __restrict__ bv,
                                                   const float* __restrict__ bs,
                                                   float* __restrict__ out) {
  int j = blockIdx.x * 256 + threadIdx.x;
  if (j >= 512) return;
  const float* src = (j < 128) ? bq : (j < 256) ? bk : (j < 384) ? bv : bs;
  out[j] = src[j & 127];
}

// ---------------- typed stores ----------------
__device__ inline void store4h(__half* p, float4 v) {
  __half2 h01 = __floats2half2_rn(v.x, v.y);
  __half2 h23 = __floats2half2_rn(v.z, v.w);
  uint2 u;
  u.x = *(unsigned int*)&h01;
  u.y = *(unsigned int*)&h23;
  *(uint2*)p = u;
}

// ---------------- MFMA GEMM ----------------
// in [Nrows][K] fp32; Wt [NCT*16][K] fp16 (pre-transposed); bias [NCT*16] fp32.
// QKVS: cols 0-127 -> oq (fp16), 128-255 -> ok, 256-383 -> ov, 384-511 -> os (fp32,
// may alias `in`: each lane fully reads its own row before writing it).
// Wave computes D = W'·H^T via mfma(w_frag, h_frag): lane (l), reg r holds
// out[row = row0+16w+(l&15)][col = ct*16+(l>>4)*4+r].
template <int K, int NCT, bool QKVS>
__global__ __launch_bounds__(256) void mfma_gemm_kernel(
    const float* in, const __half* __restrict__ Wt, const float* __restrict__ bias,
    __half* __restrict__ oq, __half* __restrict__ ok, __half* __restrict__ ov,
    float* os) {
  const int tid = threadIdx.x;
  const int w = tid >> 6, l = tid & 63;
  const int lo = l & 15, hi = l >> 4;
  const size_t row = (size_t)blockIdx.x * 64 + w * 16 + lo;

  // A-side (h) fragments: 8 consecutive fp32 of own row per k-step, cvt fp16
  half8 af[K / 32];
  #pragma unroll
  for (int s = 0; s < K / 32; ++s) {
    const float* sp = in + row * K + s * 32 + hi * 8;
    float4 f0 = *(const float4*)sp;
    float4 f1 = *(const float4*)(sp + 4);
    half8 a;
    a[0] = (_Float16)f0.x; a[1] = (_Float16)f0.y; a[2] = (_Float16)f0.z; a[3] = (_Float16)f0.w;
    a[4] = (_Float16)f1.x; a[5] = (_Float16)f1.y; a[6] = (_Float16)f1.z; a[7] = (_Float16)f1.w;
    af[s] = a;
  }

  #pragma unroll 4
  for (int ct = 0; ct < NCT; ++ct) {
    f32x4 c = {0.f, 0.f, 0.f, 0.f};
    #pragma unroll
    for (int s = 0; s < K / 32; ++s) {
      half8 bf = *(const half8*)(Wt + ((size_t)(ct * 16 + lo) * K + s * 32 + hi * 8));
      c = __builtin_amdgcn_mfma_f32_16x16x32_f16(bf, af[s], c, 0, 0, 0);
    }
    const int col0 = ct * 16 + hi * 4;
    float4 b4 = *(const float4*)(bias + col0);
    float4 o;
    o.x = c[0] + b4.x; o.y = c[1] + b4.y; o.z = c[2] + b4.z; o.w = c[3] + b4.w;
    if (QKVS) {
      const int mid = col0 >> 7, cc = col0 & 127;
      if (mid == 0)      store4h(oq + row * 128 + cc, o);
      else if (mid == 1) store4h(ok + row * 128 + cc, o);
      else if (mid == 2) store4h(ov + row * 128 + cc, o);
      else               *(float4*)(os + row * 128 + cc) = o;
    } else {
      *(float4*)(os + row * 128 + col0) = o;
    }
  }
}

// ---------------- node-centric transformer conv (one wave per node, LDS-free) ----------------
// h holds s = h_prev@ws+bs on entry; writes relu(s + softmax-agg) back to h.
__global__ __launch_bounds__(256) void node_kernel(
    const __half* __restrict__ q, const __half* __restrict__ k, const __half* __restrict__ v,
    float* __restrict__ h, const float* __restrict__ edge_attr,
    const float* __restrict__ we,
    const int* __restrict__ offs, const int* __restrict__ csr_src,
    const int* __restrict__ csr_eid) {
  const int wid = threadIdx.x >> 6, lane = threadIdx.x & 63;
  const int node = __builtin_amdgcn_readfirstlane(blockIdx.x * 4 + wid);
  const int c0 = lane * 2;
  const float inv_sqrt_d = 0.08838834764831845f;  // 1/sqrt(128)

  // we columns (c0, c0+1) for all 16 bond features -> registers
  float2 wreg[16];
  #pragma unroll
  for (int f = 0; f < 16; ++f)
    wreg[f] = *(const float2*)(we + f * D + c0);

  float2 qv = __half22float2(((const __half2*)q)[(size_t)node * 64 + lane]);
  qv.x *= inv_sqrt_d; qv.y *= inv_sqrt_d;
  float2 sv = *(const float2*)(h + (size_t)node * D + c0);

  const int eb = offs[node], ee = offs[node + 1];
  float m = -3.0e38f, den = 0.f, accx = 0.f, accy = 0.f;

  // 2-deep software pipeline over incoming edges
  float4 a0n = {0,0,0,0}, a1n = {0,0,0,0}, a2n = {0,0,0,0}, a3n = {0,0,0,0};
  float2 kvn = {0.f, 0.f}, vvn = {0.f, 0.f};
  int p = eb;
  if (p < ee) {
    int src = __builtin_amdgcn_readfirstlane(csr_src[p]);
    int eid = __builtin_amdgcn_readfirstlane(csr_eid[p]);
    const float* ea = edge_attr + (size_t)eid * 16;
    a0n = *(const float4*)(ea + 0);  a1n = *(const float4*)(ea + 4);
    a2n = *(const float4*)(ea + 8);  a3n = *(const float4*)(ea + 12);
    kvn = __half22float2(((const __half2*)k)[(size_t)src * 64 + lane]);
    vvn = __half22float2(((const __half2*)v)[(size_t)src * 64 + lane]);
  }
  while (p < ee) {
    float4 a0 = a0n, a1 = a1n, a2 = a2n, a3 = a3n;
    float2 kv = kvn, vv = vvn;
    ++p;
    if (p < ee) {
      int src = __builtin_amdgcn_readfirstlane(csr_src[p]);
      int eid = __builtin_amdgcn_readfirstlane(csr_eid[p]);
      const float* ea = edge_attr + (size_t)eid * 16;
      a0n = *(const float4*)(ea + 0);  a1n = *(const float4*)(ea + 4);
      a2n = *(const float4*)(ea + 8);  a3n = *(const float4*)(ea + 12);
      kvn = __half22float2(((const __half2*)k)[(size_t)src * 64 + lane]);
      vvn = __half22float2(((const __half2*)v)[(size_t)src * 64 + lane]);
    }
    // edge projection: ev = ea @ we (2 columns per lane)
    float ea16[16] = {a0.x, a0.y, a0.z, a0.w, a1.x, a1.y, a1.z, a1.w,
                      a2.x, a2.y, a2.z, a2.w, a3.x, a3.y, a3.z, a3.w};
    float evx = 0.f, evy = 0.f;
    #pragma unroll
    for (int f = 0; f < 16; ++f) {
      evx += ea16[f] * wreg[f].x;
      evy += ea16[f] * wreg[f].y;
    }
    float pa = qv.x * (kv.x + evx) + qv.y * (kv.y + evy);
    #pragma unroll
    for (int off = 32; off > 0; off >>= 1) pa += __shfl_xor(pa, off, 64);
    float vjx = vv.x + evx, vjy = vv.y + evy;
    float mn = fmaxf(m, pa);
    float esc = __expf(m - mn);
    float ew = __expf(pa - mn);
    den = den * esc + ew;
    accx = accx * esc + ew * vjx;
    accy = accy * esc + ew * vjy;
    m = mn;
  }
  if (den > 0.f) {
    sv.x += accx / den;
    sv.y += accy / den;
  }
  sv.x = fmaxf(sv.x, 0.f);
  sv.y = fmaxf(sv.y, 0.f);
  *(float2*)(h + (size_t)node * D + c0) = sv;
}

// ---------------- segmented mean-pool (batch sorted) ----------------
__global__ __launch_bounds__(64) void pool_kernel(const float* __restrict__ h,
                                                  const int* __restrict__ batch,
                                                  float* __restrict__ hg,
                                                  float* __restrict__ cnt, int n) {
  int base = blockIdx.x * 128;
  int lane = threadIdx.x;
  float2 acc = {0.f, 0.f};
  float run = 0.f;
  int cur = batch[base];
  for (int i = 0; i < 128; ++i) {
    int node = base + i;
    int g = batch[node];
    if (g != cur) {
      atomicAdd(&hg[(size_t)cur * D + 2 * lane], acc.x);
      atomicAdd(&hg[(size_t)cur * D + 2 * lane + 1], acc.y);
      if (lane == 0) atomicAdd(&cnt[cur], run);
      acc.x = acc.y = 0.f; run = 0.f; cur = g;
    }
    float2 hv = *(const float2*)(h + (size_t)node * D + 2 * lane);
    acc.x += hv.x; acc.y += hv.y; run += 1.f;
  }
  atomicAdd(&hg[(size_t)cur * D + 2 * lane], acc.x);
  atomicAdd(&hg[(size_t)cur * D + 2 * lane + 1], acc.y);
  if (lane == 0) atomicAdd(&cnt[cur], run);
}

// ---------------- head: mean, fc2+relu, fc3 (one wave per graph) ----------------
__global__ __launch_bounds__(256) void head_kernel(const float* __restrict__ hg,
                                                   const float* __restrict__ cnt,
                                                   const float* __restrict__ w2,
                                                   const float* __restrict__ b2,
                                                   const float* __restrict__ w3,
                                                   const float* __restrict__ b3,
                                                   float* __restrict__ out) {
  __shared__ float w2s[128 * 16];
  __shared__ float rowb[4][128];
  for (int i = threadIdx.x; i < (128 * 16) / 4; i += 256)
    ((float4*)w2s)[i] = ((const float4*)w2)[i];
  int wid = threadIdx.x >> 6, lane = threadIdx.x & 63;
  int g = blockIdx.x * 4 + wid;
  float inv = 1.0f / fmaxf(cnt[g], 1.0f);
  rowb[wid][lane] = hg[(size_t)g * D + lane] * inv;
  rowb[wid][lane + 64] = hg[(size_t)g * D + 64 + lane] * inv;
  __syncthreads();
  float t = 0.f;
  if (lane < 16) {
    float a = b2[lane];
    for (int d = 0; d < 128; ++d) a += rowb[wid][d] * w2s[d * 16 + lane];
    t = fmaxf(a, 0.f) * w3[lane];
  }
  #pragma unroll
  for (int off = 8; off > 0; off >>= 1) t += __shfl_xor(t, off, 64);
  if (lane == 0) out[g] = t + b3[0];
}

// ---------------- launch ----------------
extern "C" void kernel_launch(void* const* d_in, const int* in_sizes, int n_in,
                              void* d_out, int out_size, void* d_ws, size_t ws_size,
                              hipStream_t stream) {
  const float* x = (const float*)d_in[0];
  const int* eidx = (const int*)d_in[1];
  const float* eattr = (const float*)d_in[2];
  const int* batch = (const int*)d_in[3];
  const float* fc1_w = (const float*)d_in[4];
  const float* fc1_b = (const float*)d_in[5];
  const float* WQ[3] = {(const float*)d_in[6], (const float*)d_in[15], (const float*)d_in[24]};
  const float* BQ[3] = {(const float*)d_in[7], (const float*)d_in[16], (const float*)d_in[25]};
  const float* WK[3] = {(const float*)d_in[8], (const float*)d_in[17], (const float*)d_in[26]};
  const float* BK[3] = {(const float*)d_in[9], (const float*)d_in[18], (const float*)d_in[27]};
  const float* WV[3] = {(const float*)d_in[10], (const float*)d_in[19], (const float*)d_in[28]};
  const float* BV[3] = {(const float*)d_in[11], (const float*)d_in[20], (const float*)d_in[29]};
  const float* WE[3] = {(const float*)d_in[12], (const float*)d_in[21], (const float*)d_in[30]};
  const float* WS[3] = {(const float*)d_in[13], (const float*)d_in[22], (const float*)d_in[31]};
  const float* BS[3] = {(const float*)d_in[14], (const float*)d_in[23], (const float*)d_in[32]};
  const float* fc2_w = (const float*)d_in[33];
  const float* fc2_b = (const float*)d_in[34];
  const float* fc3_w = (const float*)d_in[35];
  const float* fc3_b = (const float*)d_in[36];

  const int N = in_sizes[0] / 64;
  const int E = in_sizes[1] / 2;
  const int G = out_size;  // DIM_OUT = 1
  const int* srcs = eidx;
  const int* dsts = eidx + E;
  const size_t ND = (size_t)N * D;

  char* base = (char*)d_ws;
  size_t off = 0;
  auto alloc = [&](size_t bytes) {
    void* p = base + off;
    off = (off + bytes + 255) & ~(size_t)255;
    return p;
  };
  // zeroed region first (hg, cnt, counts, cursor contiguous — all sizes multiple of 256B)
  float* hg = (float*)alloc((size_t)G * D * 4);
  float* cntf = (float*)alloc((size_t)G * 4);
  int* counts = (int*)alloc((size_t)N * 4);
  int* cursor = (int*)alloc((size_t)N * 4);
  size_t zero_bytes = (size_t)G * D * 4 + (size_t)G * 4 + 2 * (size_t)N * 4;
  int* incl = (int*)alloc((size_t)N * 4);
  int* offs = (int*)alloc((size_t)(N + 4) * 4);
  int* bsum = (int*)alloc(512 * 4);
  int* csr_src = (int*)alloc((size_t)E * 4);
  int* csr_eid = (int*)alloc((size_t)E * 4);
  float* h = (float*)alloc(ND * 4);
  __half* q = (__half*)alloc(ND * 2);
  __half* k = (__half*)alloc(ND * 2);
  __half* v = (__half*)alloc(ND * 2);
  __half* Wt[3];
  float* bc[3];
  for (int l = 0; l < 3; ++l) {
    Wt[l] = (__half*)alloc(512 * 128 * 2);
    bc[l] = (float*)alloc(512 * 4);
  }
  __half* fc1t = (__half*)alloc(128 * 64 * 2);
  if (off > ws_size) return;  // ws too small (diagnostic: stub-identical absmax)

  hipMemsetAsync(hg, 0, zero_bytes, stream);

  // weight prep: transpose+fp16 (q|k|v|s per layer), bias concat, fc1 transpose
  for (int l = 0; l < 3; ++l) {
    convw_kernel<<<64, 256, 0, stream>>>(WQ[l], Wt[l] + 0 * 16384, 128, 128);
    convw_kernel<<<64, 256, 0, stream>>>(WK[l], Wt[l] + 1 * 16384, 128, 128);
    convw_kernel<<<64, 256, 0, stream>>>(WV[l], Wt[l] + 2 * 16384, 128, 128);
    convw_kernel<<<64, 256, 0, stream>>>(WS[l], Wt[l] + 3 * 16384, 128, 128);
    bcat_kernel<<<2, 256, 0, stream>>>(BQ[l], BK[l], BV[l], BS[l], bc[l]);
  }
  convw_kernel<<<32, 256, 0, stream>>>(fc1_w, fc1t, 128, 64);

  // CSR build (deterministic after sort)
  hist_kernel<<<E / 256, 256, 0, stream>>>(dsts, counts, E);
  scan_a_kernel<<<N / 256, 256, 0, stream>>>(counts, incl, bsum);
  scan_b_kernel<<<1, 512, 0, stream>>>(bsum);
  scan_c_kernel<<<N / 256, 256, 0, stream>>>(incl, counts, bsum, offs, N, E);
  scatter_kernel<<<E / 256, 256, 0, stream>>>(srcs, dsts, offs, cursor, csr_src, csr_eid, E);
  sort_kernel<<<N / 256, 256, 0, stream>>>(offs, csr_eid, csr_src, N);

  // fc1: h = x @ fc1_w + fc1_b  (MFMA, K=64, 128 cols)
  mfma_gemm_kernel<64, 8, false><<<N / 64, 256, 0, stream>>>(
      x, fc1t, fc1_b, nullptr, nullptr, nullptr, h);

  // 3 transformer-conv layers
  for (int l = 0; l < 3; ++l) {
    mfma_gemm_kernel<128, 32, true><<<N / 64, 256, 0, stream>>>(
        h, Wt[l], bc[l], q, k, v, h);
    node_kernel<<<N / 4, 256, 0, stream>>>(q, k, v, h, eattr, WE[l],
                                           offs, csr_src, csr_eid);
  }

  // mean pool + head
  pool_kernel<<<N / 128, 64, 0, stream>>>(h, batch, hg, cntf, N);
  head_kernel<<<G / 4, 256, 0, stream>>>(hg, cntf, fc2_w, fc2_b, fc3_w, fc3_b, (float*)d_out);
}

// Round 7
// 654.709 us; speedup vs baseline: 4.4698x; 1.3604x over previous
//
#include <hip/hip_runtime.h>
#include <hip/hip_fp16.h>

// TFNN: 3-layer TransformerConv GNN.
// Round 7: round-6 structure with the Wc staging copy-width bug fixed:
// uint2 (8B) -> uint4 (16B) to match the 8-half stride. alignas(16) on Wc.

#define D 128

typedef _Float16 half8 __attribute__((ext_vector_type(8)));
typedef float f32x4 __attribute__((ext_vector_type(4)));

// ---------------- CSR build ----------------
__global__ __launch_bounds__(256) void hist_kernel(const int* __restrict__ dst,
                                                   int* __restrict__ counts, int e) {
  int i = blockIdx.x * 256 + threadIdx.x;
  if (i < e) atomicAdd(&counts[dst[i]], 1);
}

__global__ __launch_bounds__(256) void scan_a_kernel(const int* __restrict__ counts,
                                                     int* __restrict__ incl,
                                                     int* __restrict__ bsum) {
  int gid = blockIdx.x * 256 + threadIdx.x;
  int lane = threadIdx.x & 63, wid = threadIdx.x >> 6;
  int v = counts[gid];
  int s = v;
  #pragma unroll
  for (int off = 1; off < 64; off <<= 1) {
    int t = __shfl_up(s, off, 64);
    if (lane >= off) s += t;
  }
  __shared__ int wsum[4];
  if (lane == 63) wsum[wid] = s;
  __syncthreads();
  #pragma unroll
  for (int w = 0; w < 3; ++w)
    if (wid > w) s += wsum[w];
  incl[gid] = s;
  if (threadIdx.x == 255) bsum[blockIdx.x] = s;
}

__global__ __launch_bounds__(512) void scan_b_kernel(int* __restrict__ bs) {
  int tid = threadIdx.x;
  int lane = tid & 63, wid = tid >> 6;
  int v = bs[tid];
  int s = v;
  #pragma unroll
  for (int off = 1; off < 64; off <<= 1) {
    int t = __shfl_up(s, off, 64);
    if (lane >= off) s += t;
  }
  __shared__ int wsum[8];
  if (lane == 63) wsum[wid] = s;
  __syncthreads();
  #pragma unroll
  for (int w = 0; w < 7; ++w)
    if (wid > w) s += wsum[w];
  bs[tid] = s - v;  // exclusive block prefix
}

__global__ __launch_bounds__(256) void scan_c_kernel(const int* __restrict__ incl,
                                                     const int* __restrict__ counts,
                                                     const int* __restrict__ bsum,
                                                     int* __restrict__ offs, int n, int e) {
  int gid = blockIdx.x * 256 + threadIdx.x;
  if (gid < n) offs[gid] = incl[gid] - counts[gid] + bsum[blockIdx.x];
  if (gid == 0) offs[n] = e;
}

__global__ __launch_bounds__(256) void scatter_kernel(const int* __restrict__ srcs,
                                                      const int* __restrict__ dsts,
                                                      const int* __restrict__ offs,
                                                      int* __restrict__ cursor,
                                                      int* __restrict__ csr_src,
                                                      int* __restrict__ csr_eid, int e) {
  int i = blockIdx.x * 256 + threadIdx.x;
  if (i >= e) return;
  int d = dsts[i];
  int slot = atomicAdd(&cursor[d], 1);
  int p = offs[d] + slot;
  csr_src[p] = srcs[i];
  csr_eid[p] = i;
}

// deterministic order: sort each node's incoming edge list by edge id
__global__ __launch_bounds__(256) void sort_kernel(const int* __restrict__ offs,
                                                   int* __restrict__ eid,
                                                   int* __restrict__ srcs, int n) {
  int i = blockIdx.x * 256 + threadIdx.x;
  if (i >= n) return;
  int b = offs[i], e = offs[i + 1];
  for (int p = b + 1; p < e; ++p) {
    int ke = eid[p], ks = srcs[p];
    int q = p - 1;
    while (q >= b && eid[q] > ke) {
      eid[q + 1] = eid[q]; srcs[q + 1] = srcs[q]; --q;
    }
    eid[q + 1] = ke; srcs[q + 1] = ks;
  }
}

// ---------------- weight transpose + fp16 convert: out[n][kk] = W[kk][n] ----------------
__global__ __launch_bounds__(256) void convw_kernel(const float* __restrict__ W,
                                                    __half* __restrict__ out,
                                                    int ncols, int K) {
  int idx = blockIdx.x * 256 + threadIdx.x;
  if (idx >= ncols * K) return;
  int n = idx / K, kk = idx - n * K;
  out[idx] = __float2half(W[(size_t)kk * ncols + n]);
}

// bias concat: out[0:512] = bq|bk|bv|bs
__global__ __launch_bounds__(256) void bcat_kernel(const float* __restrict__ bq,
                                                   const float* __restrict__ bk,
                                                   const float* __restrict__ bv,
                                                   const float* __restrict__ bs,
                                                   float* __restrict__ out) {
  int j = blockIdx.x * 256 + threadIdx.x;
  if (j >= 512) return;
  const float* src = (j < 128) ? bq : (j < 256) ? bk : (j < 384) ? bv : bs;
  out[j] = src[j & 127];
}

// ---------------- typed stores ----------------
__device__ inline void store4h(__half* p, float4 v) {
  __half2 h01 = __floats2half2_rn(v.x, v.y);
  __half2 h23 = __floats2half2_rn(v.z, v.w);
  uint2 u;
  u.x = *(unsigned int*)&h01;
  u.y = *(unsigned int*)&h23;
  *(uint2*)p = u;
}

// ---------------- MFMA GEMM (round-4 structure + LDS-staged W chunks) ----------------
// in [Nrows][K] fp32; Wt [NCT*16][K] fp16 (pre-transposed); bias [NCT*16] fp32.
// QKVS: cols 0-127 -> oq (fp16), 128-255 -> ok, 256-383 -> ov, 384-511 -> os (fp32,
// may alias `in`: each lane fully reads its own row before any store).
// Wave computes D = W'·H^T via mfma(w_frag, h_frag): lane (l), reg r holds
// out[row = row0+16w+(l&15)][col = ct*16+(l>>4)*4+r].
template <int K, int NCT, bool QKVS>
__global__ __launch_bounds__(256) void mfma_gemm_kernel(
    const float* in, const __half* __restrict__ Wt, const float* __restrict__ bias,
    __half* __restrict__ oq, __half* __restrict__ ok, __half* __restrict__ ov,
    float* os) {
  constexpr int WST = K + 8;  // Wc row stride in halfs; (K+8)*2 bytes % 16 == 0
  __shared__ alignas(16) __half Wc[128 * WST];  // current 128-col W chunk
  const int tid = threadIdx.x;
  const int w = tid >> 6, l = tid & 63;
  const int lo = l & 15, hi = l >> 4;
  const size_t row = (size_t)blockIdx.x * 64 + w * 16 + lo;

  // A-side (h) fragments: 8 consecutive fp32 of own row per k-step, cvt fp16
  // (identical to round 4 — all reads of `in` complete before any store to os)
  half8 af[K / 32];
  #pragma unroll
  for (int s = 0; s < K / 32; ++s) {
    const float* sp = in + row * K + s * 32 + hi * 8;
    float4 f0 = *(const float4*)sp;
    float4 f1 = *(const float4*)(sp + 4);
    half8 a;
    a[0] = (_Float16)f0.x; a[1] = (_Float16)f0.y; a[2] = (_Float16)f0.z; a[3] = (_Float16)f0.w;
    a[4] = (_Float16)f1.x; a[5] = (_Float16)f1.y; a[6] = (_Float16)f1.z; a[7] = (_Float16)f1.w;
    af[s] = a;
  }

  // chunk loop: 128 output cols per chunk, W chunk staged in LDS
  #pragma unroll 1
  for (int ch = 0; ch < NCT / 8; ++ch) {
    __syncthreads();  // protect Wc reuse across chunks
    // each idx copies 8 halfs (16B): kk steps in 8-half units, uint4 = 16B. FIXED.
    #pragma unroll
    for (int i = 0; i < 128 * K / 8 / 256; ++i) {
      int idx = i * 256 + tid;
      int col = idx / (K / 8), kk = (idx % (K / 8)) * 8;
      *(uint4*)&Wc[col * WST + kk] =
          *(const uint4*)(Wt + (size_t)(ch * 128 + col) * K + kk);
    }
    __syncthreads();

    #pragma unroll
    for (int t = 0; t < 8; ++t) {
      f32x4 c = {0.f, 0.f, 0.f, 0.f};
      #pragma unroll
      for (int s = 0; s < K / 32; ++s) {
        half8 bf = *(const half8*)&Wc[(t * 16 + lo) * WST + s * 32 + hi * 8];
        c = __builtin_amdgcn_mfma_f32_16x16x32_f16(bf, af[s], c, 0, 0, 0);
      }
      const int col0 = ch * 128 + t * 16 + hi * 4;
      float4 b4 = *(const float4*)(bias + col0);
      float4 o;
      o.x = c[0] + b4.x; o.y = c[1] + b4.y; o.z = c[2] + b4.z; o.w = c[3] + b4.w;
      if (QKVS) {
        const int mid = col0 >> 7, cc = col0 & 127;
        if (mid == 0)      store4h(oq + row * 128 + cc, o);
        else if (mid == 1) store4h(ok + row * 128 + cc, o);
        else if (mid == 2) store4h(ov + row * 128 + cc, o);
        else               *(float4*)(os + row * 128 + cc) = o;
      } else {
        *(float4*)(os + row * 128 + col0) = o;
      }
    }
  }
}

// ---------------- node-centric transformer conv (one wave per node, LDS-free) ----------------
// h holds s = h_prev@ws+bs on entry; writes relu(s + softmax-agg) back to h.
__global__ __launch_bounds__(256) void node_kernel(
    const __half* __restrict__ q, const __half* __restrict__ k, const __half* __restrict__ v,
    float* __restrict__ h, const float* __restrict__ edge_attr,
    const float* __restrict__ we,
    const int* __restrict__ offs, const int* __restrict__ csr_src,
    const int* __restrict__ csr_eid) {
  const int wid = threadIdx.x >> 6, lane = threadIdx.x & 63;
  const int node = __builtin_amdgcn_readfirstlane(blockIdx.x * 4 + wid);
  const int c0 = lane * 2;
  const float inv_sqrt_d = 0.08838834764831845f;  // 1/sqrt(128)

  // we columns (c0, c0+1) for all 16 bond features -> registers
  float2 wreg[16];
  #pragma unroll
  for (int f = 0; f < 16; ++f)
    wreg[f] = *(const float2*)(we + f * D + c0);

  float2 qv = __half22float2(((const __half2*)q)[(size_t)node * 64 + lane]);
  qv.x *= inv_sqrt_d; qv.y *= inv_sqrt_d;
  float2 sv = *(const float2*)(h + (size_t)node * D + c0);

  const int eb = offs[node], ee = offs[node + 1];
  float m = -3.0e38f, den = 0.f, accx = 0.f, accy = 0.f;

  // 2-deep software pipeline over incoming edges
  float4 a0n = {0,0,0,0}, a1n = {0,0,0,0}, a2n = {0,0,0,0}, a3n = {0,0,0,0};
  float2 kvn = {0.f, 0.f}, vvn = {0.f, 0.f};
  int p = eb;
  if (p < ee) {
    int src = __builtin_amdgcn_readfirstlane(csr_src[p]);
    int eid = __builtin_amdgcn_readfirstlane(csr_eid[p]);
    const float* ea = edge_attr + (size_t)eid * 16;
    a0n = *(const float4*)(ea + 0);  a1n = *(const float4*)(ea + 4);
    a2n = *(const float4*)(ea + 8);  a3n = *(const float4*)(ea + 12);
    kvn = __half22float2(((const __half2*)k)[(size_t)src * 64 + lane]);
    vvn = __half22float2(((const __half2*)v)[(size_t)src * 64 + lane]);
  }
  while (p < ee) {
    float4 a0 = a0n, a1 = a1n, a2 = a2n, a3 = a3n;
    float2 kv = kvn, vv = vvn;
    ++p;
    if (p < ee) {
      int src = __builtin_amdgcn_readfirstlane(csr_src[p]);
      int eid = __builtin_amdgcn_readfirstlane(csr_eid[p]);
      const float* ea = edge_attr + (size_t)eid * 16;
      a0n = *(const float4*)(ea + 0);  a1n = *(const float4*)(ea + 4);
      a2n = *(const float4*)(ea + 8);  a3n = *(const float4*)(ea + 12);
      kvn = __half22float2(((const __half2*)k)[(size_t)src * 64 + lane]);
      vvn = __half22float2(((const __half2*)v)[(size_t)src * 64 + lane]);
    }
    // edge projection: ev = ea @ we (2 columns per lane)
    float ea16[16] = {a0.x, a0.y, a0.z, a0.w, a1.x, a1.y, a1.z, a1.w,
                      a2.x, a2.y, a2.z, a2.w, a3.x, a3.y, a3.z, a3.w};
    float evx = 0.f, evy = 0.f;
    #pragma unroll
    for (int f = 0; f < 16; ++f) {
      evx += ea16[f] * wreg[f].x;
      evy += ea16[f] * wreg[f].y;
    }
    float pa = qv.x * (kv.x + evx) + qv.y * (kv.y + evy);
    #pragma unroll
    for (int off = 32; off > 0; off >>= 1) pa += __shfl_xor(pa, off, 64);
    float vjx = vv.x + evx, vjy = vv.y + evy;
    float mn = fmaxf(m, pa);
    float esc = __expf(m - mn);
    float ew = __expf(pa - mn);
    den = den * esc + ew;
    accx = accx * esc + ew * vjx;
    accy = accy * esc + ew * vjy;
    m = mn;
  }
  if (den > 0.f) {
    sv.x += accx / den;
    sv.y += accy / den;
  }
  sv.x = fmaxf(sv.x, 0.f);
  sv.y = fmaxf(sv.y, 0.f);
  *(float2*)(h + (size_t)node * D + c0) = sv;
}

// ---------------- segmented mean-pool (batch sorted) ----------------
__global__ __launch_bounds__(64) void pool_kernel(const float* __restrict__ h,
                                                  const int* __restrict__ batch,
                                                  float* __restrict__ hg,
                                                  float* __restrict__ cnt, int n) {
  int base = blockIdx.x * 128;
  int lane = threadIdx.x;
  float2 acc = {0.f, 0.f};
  float run = 0.f;
  int cur = batch[base];
  for (int i = 0; i < 128; ++i) {
    int node = base + i;
    int g = batch[node];
    if (g != cur) {
      atomicAdd(&hg[(size_t)cur * D + 2 * lane], acc.x);
      atomicAdd(&hg[(size_t)cur * D + 2 * lane + 1], acc.y);
      if (lane == 0) atomicAdd(&cnt[cur], run);
      acc.x = acc.y = 0.f; run = 0.f; cur = g;
    }
    float2 hv = *(const float2*)(h + (size_t)node * D + 2 * lane);
    acc.x += hv.x; acc.y += hv.y; run += 1.f;
  }
  atomicAdd(&hg[(size_t)cur * D + 2 * lane], acc.x);
  atomicAdd(&hg[(size_t)cur * D + 2 * lane + 1], acc.y);
  if (lane == 0) atomicAdd(&cnt[cur], run);
}

// ---------------- head: mean, fc2+relu, fc3 (one wave per graph) ----------------
__global__ __launch_bounds__(256) void head_kernel(const float* __restrict__ hg,
                                                   const float* __restrict__ cnt,
                                                   const float* __restrict__ w2,
                                                   const float* __restrict__ b2,
                                                   const float* __restrict__ w3,
                                                   const float* __restrict__ b3,
                                                   float* __restrict__ out) {
  __shared__ float w2s[128 * 16];
  __shared__ float rowb[4][128];
  for (int i = threadIdx.x; i < (128 * 16) / 4; i += 256)
    ((float4*)w2s)[i] = ((const float4*)w2)[i];
  int wid = threadIdx.x >> 6, lane = threadIdx.x & 63;
  int g = blockIdx.x * 4 + wid;
  float inv = 1.0f / fmaxf(cnt[g], 1.0f);
  rowb[wid][lane] = hg[(size_t)g * D + lane] * inv;
  rowb[wid][lane + 64] = hg[(size_t)g * D + 64 + lane] * inv;
  __syncthreads();
  float t = 0.f;
  if (lane < 16) {
    float a = b2[lane];
    for (int d = 0; d < 128; ++d) a += rowb[wid][d] * w2s[d * 16 + lane];
    t = fmaxf(a, 0.f) * w3[lane];
  }
  #pragma unroll
  for (int off = 8; off > 0; off >>= 1) t += __shfl_xor(t, off, 64);
  if (lane == 0) out[g] = t + b3[0];
}

// ---------------- launch ----------------
extern "C" void kernel_launch(void* const* d_in, const int* in_sizes, int n_in,
                              void* d_out, int out_size, void* d_ws, size_t ws_size,
                              hipStream_t stream) {
  const float* x = (const float*)d_in[0];
  const int* eidx = (const int*)d_in[1];
  const float* eattr = (const float*)d_in[2];
  const int* batch = (const int*)d_in[3];
  const float* fc1_w = (const float*)d_in[4];
  const float* fc1_b = (const float*)d_in[5];
  const float* WQ[3] = {(const float*)d_in[6], (const float*)d_in[15], (const float*)d_in[24]};
  const float* BQ[3] = {(const float*)d_in[7], (const float*)d_in[16], (const float*)d_in[25]};
  const float* WK[3] = {(const float*)d_in[8], (const float*)d_in[17], (const float*)d_in[26]};
  const float* BK[3] = {(const float*)d_in[9], (const float*)d_in[18], (const float*)d_in[27]};
  const float* WV[3] = {(const float*)d_in[10], (const float*)d_in[19], (const float*)d_in[28]};
  const float* BV[3] = {(const float*)d_in[11], (const float*)d_in[20], (const float*)d_in[29]};
  const float* WE[3] = {(const float*)d_in[12], (const float*)d_in[21], (const float*)d_in[30]};
  const float* WS[3] = {(const float*)d_in[13], (const float*)d_in[22], (const float*)d_in[31]};
  const float* BS[3] = {(const float*)d_in[14], (const float*)d_in[23], (const float*)d_in[32]};
  const float* fc2_w = (const float*)d_in[33];
  const float* fc2_b = (const float*)d_in[34];
  const float* fc3_w = (const float*)d_in[35];
  const float* fc3_b = (const float*)d_in[36];

  const int N = in_sizes[0] / 64;
  const int E = in_sizes[1] / 2;
  const int G = out_size;  // DIM_OUT = 1
  const int* srcs = eidx;
  const int* dsts = eidx + E;
  const size_t ND = (size_t)N * D;

  char* base = (char*)d_ws;
  size_t off = 0;
  auto alloc = [&](size_t bytes) {
    void* p = base + off;
    off = (off + bytes + 255) & ~(size_t)255;
    return p;
  };
  // zeroed region first (hg, cnt, counts, cursor contiguous — all sizes multiple of 256B)
  float* hg = (float*)alloc((size_t)G * D * 4);
  float* cntf = (float*)alloc((size_t)G * 4);
  int* counts = (int*)alloc((size_t)N * 4);
  int* cursor = (int*)alloc((size_t)N * 4);
  size_t zero_bytes = (size_t)G * D * 4 + (size_t)G * 4 + 2 * (size_t)N * 4;
  int* incl = (int*)alloc((size_t)N * 4);
  int* offs = (int*)alloc((size_t)(N + 4) * 4);
  int* bsum = (int*)alloc(512 * 4);
  int* csr_src = (int*)alloc((size_t)E * 4);
  int* csr_eid = (int*)alloc((size_t)E * 4);
  float* h = (float*)alloc(ND * 4);
  __half* q = (__half*)alloc(ND * 2);
  __half* k = (__half*)alloc(ND * 2);
  __half* v = (__half*)alloc(ND * 2);
  __half* Wt[3];
  float* bc[3];
  for (int l = 0; l < 3; ++l) {
    Wt[l] = (__half*)alloc(512 * 128 * 2);
    bc[l] = (float*)alloc(512 * 4);
  }
  __half* fc1t = (__half*)alloc(128 * 64 * 2);
  if (off > ws_size) return;  // ws too small (diagnostic: stub-identical absmax)

  hipMemsetAsync(hg, 0, zero_bytes, stream);

  // weight prep: transpose+fp16 (q|k|v|s per layer), bias concat, fc1 transpose
  for (int l = 0; l < 3; ++l) {
    convw_kernel<<<64, 256, 0, stream>>>(WQ[l], Wt[l] + 0 * 16384, 128, 128);
    convw_kernel<<<64, 256, 0, stream>>>(WK[l], Wt[l] + 1 * 16384, 128, 128);
    convw_kernel<<<64, 256, 0, stream>>>(WV[l], Wt[l] + 2 * 16384, 128, 128);
    convw_kernel<<<64, 256, 0, stream>>>(WS[l], Wt[l] + 3 * 16384, 128, 128);
    bcat_kernel<<<2, 256, 0, stream>>>(BQ[l], BK[l], BV[l], BS[l], bc[l]);
  }
  convw_kernel<<<32, 256, 0, stream>>>(fc1_w, fc1t, 128, 64);

  // CSR build (deterministic after sort)
  hist_kernel<<<E / 256, 256, 0, stream>>>(dsts, counts, E);
  scan_a_kernel<<<N / 256, 256, 0, stream>>>(counts, incl, bsum);
  scan_b_kernel<<<1, 512, 0, stream>>>(bsum);
  scan_c_kernel<<<N / 256, 256, 0, stream>>>(incl, counts, bsum, offs, N, E);
  scatter_kernel<<<E / 256, 256, 0, stream>>>(srcs, dsts, offs, cursor, csr_src, csr_eid, E);
  sort_kernel<<<N / 256, 256, 0, stream>>>(offs, csr_eid, csr_src, N);

  // fc1: h = x @ fc1_w + fc1_b  (MFMA, K=64, 128 cols)
  mfma_gemm_kernel<64, 8, false><<<N / 64, 256, 0, stream>>>(
      x, fc1t, fc1_b, nullptr, nullptr, nullptr, h);

  // 3 transformer-conv layers
  for (int l = 0; l < 3; ++l) {
    mfma_gemm_kernel<128, 32, true><<<N / 64, 256, 0, stream>>>(
        h, Wt[l], bc[l], q, k, v, h);
    node_kernel<<<N / 4, 256, 0, stream>>>(q, k, v, h, eattr, WE[l],
                                           offs, csr_src, csr_eid);
  }

  // mean pool + head
  pool_kernel<<<N / 128, 64, 0, stream>>>(h, batch, hg, cntf, N);
  head_kernel<<<G / 4, 256, 0, stream>>>(hg, cntf, fc2_w, fc2_b, fc3_w, fc3_b, (float*)d_out);
}